// Round 1
// baseline (488.648 us; speedup 1.0000x reference)
//
#include <hip/hip_runtime.h>

// ---------------------------------------------------------------------------
// EdgeLLMAttentionTRTNative: live math is out = (X @ Wq^T * scale) @ Wo^T,
// plus kv_cache passthrough. Wk/Wv/rope/context inputs are dead.
//   X  : (8192, 3072) fp32   (b*s, HIDDEN)
//   Wq : (3072, 3072) fp32   (d, h)   -> B^T layout for GEMM1
//   Wo : (3072, 3072) fp32   (o, d)   -> B^T layout for GEMM2
//   out: (8192, 3072) fp32, then kv_cache (33_554_432 f32) appended.
// Round 1: m97-structure bf16 GEMM (128x128 tile, BK=32, 4 waves,
// global_load_lds width 16, mfma_f32_16x16x32_bf16).
// ---------------------------------------------------------------------------

typedef __attribute__((ext_vector_type(8))) __bf16 bf16x8;
typedef __attribute__((ext_vector_type(4))) float f32x4;

__device__ __forceinline__ unsigned short f2bf(float f) {
  union { float f; unsigned u; } v; v.f = f;
  unsigned r = v.u + 0x7fffu + ((v.u >> 16) & 1u);   // round-to-nearest-even
  return (unsigned short)(r >> 16);
}

__global__ void cast_f32_to_bf16(const float4* __restrict__ in,
                                 ushort4* __restrict__ out, int n4) {
  int i = blockIdx.x * blockDim.x + threadIdx.x;
  int stride = gridDim.x * blockDim.x;
  for (; i < n4; i += stride) {
    float4 v = in[i];
    ushort4 o;
    o.x = f2bf(v.x); o.y = f2bf(v.y); o.z = f2bf(v.z); o.w = f2bf(v.w);
    out[i] = o;
  }
}

typedef const __attribute__((address_space(1))) void* gptr_t;
typedef __attribute__((address_space(3))) void* lptr_t;

__device__ __forceinline__ void gload16(const void* g, void* l) {
  // async global->LDS, 16B per lane; LDS dest = wave-uniform base + lane*16
  __builtin_amdgcn_global_load_lds((gptr_t)g, (lptr_t)l, 16, 0, 0);
}

// C = A(MxK) * B(NxK)^T, all row-major; A,B bf16; C bf16 (scaled) or f32.
// M,N multiples of 128; K multiple of 32.
template <int OUT_BF16>
__global__ void gemm_bt(const ushort* __restrict__ A, const ushort* __restrict__ B,
                        void* __restrict__ Cv, int M, int N, int K, float scale) {
  __shared__ __align__(16) ushort As[128 * 32];
  __shared__ __align__(16) ushort Bs[128 * 32];

  const int t    = threadIdx.x;
  const int w    = t >> 6;
  const int lane = t & 63;
  const int wr   = w >> 1, wc = w & 1;      // 2x2 wave grid, each wave 64x64
  const int fr   = lane & 15;               // fragment row (A row / B row)
  const int kq   = (lane >> 4) << 3;        // K sub-offset 0/8/16/24

  const int rowBase = blockIdx.y * 128;
  const int colBase = blockIdx.x * 128;

  // Staging geometry: tile is 128x32 bf16 = 8192B; 256 thr * 16B = 4096B/chunk.
  const int e0 = t * 8;                      // chunk 0 covers rows 0..63
  const int r0 = e0 >> 5, c0 = e0 & 31;
  const int e1 = 2048 + t * 8;               // chunk 1 covers rows 64..127
  const int r1 = e1 >> 5, c1 = e1 & 31;
  const ushort* Ag0 = A + (size_t)(rowBase + r0) * K + c0;
  const ushort* Ag1 = A + (size_t)(rowBase + r1) * K + c1;
  const ushort* Bg0 = B + (size_t)(colBase + r0) * K + c0;
  const ushort* Bg1 = B + (size_t)(colBase + r1) * K + c1;
  ushort* Al0 = &As[w * 512];
  ushort* Al1 = &As[2048 + w * 512];
  ushort* Bl0 = &Bs[w * 512];
  ushort* Bl1 = &Bs[2048 + w * 512];

  f32x4 acc[4][4];
#pragma unroll
  for (int m = 0; m < 4; ++m)
#pragma unroll
    for (int n = 0; n < 4; ++n)
      acc[m][n] = f32x4{0.f, 0.f, 0.f, 0.f};

  for (int k0 = 0; k0 < K; k0 += 32) {
    __syncthreads();                 // protect LDS from prior-iter readers
    gload16(Ag0 + k0, Al0);
    gload16(Ag1 + k0, Al1);
    gload16(Bg0 + k0, Bl0);
    gload16(Bg1 + k0, Bl1);
    __syncthreads();                 // compiler emits vmcnt(0) drain here

    bf16x8 a[4], b[4];
#pragma unroll
    for (int m = 0; m < 4; ++m)
      a[m] = *(const bf16x8*)&As[(wr * 64 + m * 16 + fr) * 32 + kq];
#pragma unroll
    for (int n = 0; n < 4; ++n)
      b[n] = *(const bf16x8*)&Bs[(wc * 64 + n * 16 + fr) * 32 + kq];

#pragma unroll
    for (int m = 0; m < 4; ++m)
#pragma unroll
      for (int n = 0; n < 4; ++n)
        acc[m][n] = __builtin_amdgcn_mfma_f32_16x16x32_bf16(a[m], b[n], acc[m][n], 0, 0, 0);
  }

  // C/D layout (verified m89/m91): col = lane&15, row = (lane>>4)*4 + reg
  const int orow = rowBase + wr * 64 + ((lane >> 4) << 2);
  const int ocol = colBase + wc * 64 + fr;
#pragma unroll
  for (int m = 0; m < 4; ++m)
#pragma unroll
    for (int n = 0; n < 4; ++n)
#pragma unroll
      for (int i = 0; i < 4; ++i) {
        const size_t idx = (size_t)(orow + m * 16 + i) * N + (ocol + n * 16);
        float v = acc[m][n][i] * scale;
        if (OUT_BF16) ((ushort*)Cv)[idx] = f2bf(v);
        else          ((float*)Cv)[idx]  = v;
      }
}

extern "C" void kernel_launch(void* const* d_in, const int* in_sizes, int n_in,
                              void* d_out, int out_size, void* d_ws, size_t ws_size,
                              hipStream_t stream) {
  const float* hs = (const float*)d_in[0];   // (4,2048,3072)
  const float* kv = (const float*)d_in[4];   // (4,2,8,4096,128)
  const float* Wq = (const float*)d_in[5];   // (3072,3072)
  const float* Wo = (const float*)d_in[8];   // (3072,3072)

  const int M = 8192, N = 3072, K = 3072;
  const int OUT_ELEMS = M * N;               // 25_165_824 floats

  float* out = (float*)d_out;

  // Workspace: bf16 copies of X, Wq, Wo (needs 88_080_384 B of d_ws).
  ushort* Xb  = (ushort*)d_ws;
  ushort* Wqb = Xb + (size_t)M * K;          // +50_331_648 B
  ushort* Wob = Wqb + (size_t)N * K;         // +18_874_368 B
  // bf16 intermediate Q lives in the kv-tail of d_out (50.3 MB of 134 MB);
  // it is fully overwritten by the kv_cache copy afterwards (stream-ordered).
  ushort* Qb  = (ushort*)(out + OUT_ELEMS);

  cast_f32_to_bf16<<<2048, 256, 0, stream>>>((const float4*)hs, (ushort4*)Xb, (M * K) / 4);
  cast_f32_to_bf16<<<1024, 256, 0, stream>>>((const float4*)Wq, (ushort4*)Wqb, (N * K) / 4);
  cast_f32_to_bf16<<<1024, 256, 0, stream>>>((const float4*)Wo, (ushort4*)Wob, (N * K) / 4);

  dim3 grid(N / 128, M / 128);               // (24, 64)
  const float qk_scale = 0.08838834764831845f;  // 128^-0.5
  gemm_bt<1><<<grid, 256, 0, stream>>>(Xb, Wqb, (void*)Qb, M, N, K, qk_scale);
  gemm_bt<0><<<grid, 256, 0, stream>>>(Qb, Wob, (void*)out, M, N, K, 1.0f);

  // kv_cache passthrough: overwrite the tail (including the Qb scratch region)
  hipMemcpyAsync(out + OUT_ELEMS, kv, (size_t)in_sizes[4] * sizeof(float),
                 hipMemcpyDeviceToDevice, stream);
}

// Round 2
// 379.956 us; speedup vs baseline: 1.2861x; 1.2861x over previous
//
#include <hip/hip_runtime.h>

// ---------------------------------------------------------------------------
// EdgeLLMAttentionTRTNative: live math is out = X @ (s*Wo@Wq)^T, plus
// kv_cache passthrough. Wk/Wv/rope/context inputs are dead.
// Round 2: fuse W = s*Wo@Wq (58 GF) then out = X@W^T (154.6 GF) -> 213 GF
// total (was 309). Adds cast+transpose for Wq, XCD-aware block swizzle.
// GEMM core: m97-structure (128x128 tile, BK=32, 4 waves, global_load_lds
// width 16, mfma_f32_16x16x32_bf16).
// ---------------------------------------------------------------------------

typedef __attribute__((ext_vector_type(8))) __bf16 bf16x8;
typedef __attribute__((ext_vector_type(4))) float f32x4;

__device__ __forceinline__ unsigned short f2bf(float f) {
  union { float f; unsigned u; } v; v.f = f;
  unsigned r = v.u + 0x7fffu + ((v.u >> 16) & 1u);   // round-to-nearest-even
  return (unsigned short)(r >> 16);
}

__global__ void cast_f32_to_bf16(const float4* __restrict__ in,
                                 ushort4* __restrict__ out, int n4) {
  int i = blockIdx.x * blockDim.x + threadIdx.x;
  int stride = gridDim.x * blockDim.x;
  for (; i < n4; i += stride) {
    float4 v = in[i];
    ushort4 o;
    o.x = f2bf(v.x); o.y = f2bf(v.y); o.z = f2bf(v.z); o.w = f2bf(v.w);
    out[i] = o;
  }
}

// out (C x R, bf16) = transpose of in (R x C, fp32)
__global__ void transpose_cast(const float* __restrict__ in,
                               ushort* __restrict__ out, int R, int C) {
  __shared__ float tile[32][33];           // +1 pad: bank-conflict-free
  const int tc = blockIdx.x * 32;          // col base in `in`
  const int tr = blockIdx.y * 32;          // row base in `in`
  const int lx = threadIdx.x & 31;
  const int ly = threadIdx.x >> 5;         // 0..7
#pragma unroll
  for (int i = 0; i < 32; i += 8)
    tile[ly + i][lx] = in[(size_t)(tr + ly + i) * C + (tc + lx)];
  __syncthreads();
#pragma unroll
  for (int i = 0; i < 32; i += 8)
    out[(size_t)(tc + ly + i) * R + (tr + lx)] = f2bf(tile[lx][ly + i]);
}

typedef const __attribute__((address_space(1))) void* gptr_t;
typedef __attribute__((address_space(3))) void* lptr_t;

__device__ __forceinline__ void gload16(const void* g, void* l) {
  // async global->LDS, 16B per lane; LDS dest = wave-uniform base + lane*16
  __builtin_amdgcn_global_load_lds((gptr_t)g, (lptr_t)l, 16, 0, 0);
}

// C = A(MxK) * B(NxK)^T, all row-major; A,B bf16; C bf16 (scaled) or f32.
// M,N multiples of 128; K multiple of 32. 1D grid, nwg % 8 == 0 required
// (bijective XCD swizzle).
template <int OUT_BF16>
__global__ void gemm_bt(const ushort* __restrict__ A, const ushort* __restrict__ B,
                        void* __restrict__ Cv, int M, int N, int K, float scale) {
  __shared__ __align__(16) ushort As[128 * 32];
  __shared__ __align__(16) ushort Bs[128 * 32];

  const int t    = threadIdx.x;
  const int w    = t >> 6;
  const int lane = t & 63;
  const int wr   = w >> 1, wc = w & 1;      // 2x2 wave grid, each wave 64x64
  const int fr   = lane & 15;               // fragment row (A row / B row)
  const int kq   = (lane >> 4) << 3;        // K sub-offset 0/8/16/24

  // XCD-aware bijective swizzle (T1): nwg % 8 == 0 by construction.
  const int nwg  = gridDim.x;
  const int cpx  = nwg >> 3;
  const int wg   = (blockIdx.x & 7) * cpx + (blockIdx.x >> 3);
  const int nbx  = N >> 7;
  const int bx   = wg % nbx;
  const int by   = wg / nbx;

  const int rowBase = by * 128;
  const int colBase = bx * 128;

  // Staging geometry: tile is 128x32 bf16 = 8192B; 256 thr * 16B = 4096B/chunk.
  const int e0 = t * 8;                      // chunk 0 covers rows 0..63
  const int r0 = e0 >> 5, c0 = e0 & 31;
  const int e1 = 2048 + t * 8;               // chunk 1 covers rows 64..127
  const int r1 = e1 >> 5, c1 = e1 & 31;
  const ushort* Ag0 = A + (size_t)(rowBase + r0) * K + c0;
  const ushort* Ag1 = A + (size_t)(rowBase + r1) * K + c1;
  const ushort* Bg0 = B + (size_t)(colBase + r0) * K + c0;
  const ushort* Bg1 = B + (size_t)(colBase + r1) * K + c1;
  ushort* Al0 = &As[w * 512];
  ushort* Al1 = &As[2048 + w * 512];
  ushort* Bl0 = &Bs[w * 512];
  ushort* Bl1 = &Bs[2048 + w * 512];

  f32x4 acc[4][4];
#pragma unroll
  for (int m = 0; m < 4; ++m)
#pragma unroll
    for (int n = 0; n < 4; ++n)
      acc[m][n] = f32x4{0.f, 0.f, 0.f, 0.f};

  for (int k0 = 0; k0 < K; k0 += 32) {
    __syncthreads();                 // protect LDS from prior-iter readers
    gload16(Ag0 + k0, Al0);
    gload16(Ag1 + k0, Al1);
    gload16(Bg0 + k0, Bl0);
    gload16(Bg1 + k0, Bl1);
    __syncthreads();                 // compiler emits vmcnt(0) drain here

    bf16x8 a[4], b[4];
#pragma unroll
    for (int m = 0; m < 4; ++m)
      a[m] = *(const bf16x8*)&As[(wr * 64 + m * 16 + fr) * 32 + kq];
#pragma unroll
    for (int n = 0; n < 4; ++n)
      b[n] = *(const bf16x8*)&Bs[(wc * 64 + n * 16 + fr) * 32 + kq];

#pragma unroll
    for (int m = 0; m < 4; ++m)
#pragma unroll
      for (int n = 0; n < 4; ++n)
        acc[m][n] = __builtin_amdgcn_mfma_f32_16x16x32_bf16(a[m], b[n], acc[m][n], 0, 0, 0);
  }

  // C/D layout (verified m89/m91): col = lane&15, row = (lane>>4)*4 + reg
  const int orow = rowBase + wr * 64 + ((lane >> 4) << 2);
  const int ocol = colBase + wc * 64 + fr;
#pragma unroll
  for (int m = 0; m < 4; ++m)
#pragma unroll
    for (int n = 0; n < 4; ++n)
#pragma unroll
      for (int i = 0; i < 4; ++i) {
        const size_t idx = (size_t)(orow + m * 16 + i) * N + (ocol + n * 16);
        float v = acc[m][n][i] * scale;
        if (OUT_BF16) ((ushort*)Cv)[idx] = f2bf(v);
        else          ((float*)Cv)[idx]  = v;
      }
}

extern "C" void kernel_launch(void* const* d_in, const int* in_sizes, int n_in,
                              void* d_out, int out_size, void* d_ws, size_t ws_size,
                              hipStream_t stream) {
  const float* hs = (const float*)d_in[0];   // (4,2048,3072)
  const float* kv = (const float*)d_in[4];   // (4,2,8,4096,128)
  const float* Wq = (const float*)d_in[5];   // (3072,3072) (d,h)
  const float* Wo = (const float*)d_in[8];   // (3072,3072) (o,d)

  const int M = 8192, H = 3072;
  const int OUT_ELEMS = M * H;               // 25_165_824 floats

  float* out = (float*)d_out;

  // Workspace (88_080_384 B): bf16 X, bf16 Wo, bf16 Wq^T.
  ushort* Xb   = (ushort*)d_ws;
  ushort* Wob  = Xb + (size_t)M * H;         // +50_331_648 B
  ushort* WqTb = Wob + (size_t)H * H;        // +18_874_368 B
  // Fused weight W = s*Wo@Wq (bf16, 18.9 MB) lives in the kv-tail of d_out;
  // it is fully overwritten by the kv_cache copy afterwards (stream-ordered).
  ushort* Wb   = (ushort*)(out + OUT_ELEMS);

  cast_f32_to_bf16<<<2048, 256, 0, stream>>>((const float4*)hs, (ushort4*)Xb, (M * H) / 4);
  cast_f32_to_bf16<<<1024, 256, 0, stream>>>((const float4*)Wo, (ushort4*)Wob, (H * H) / 4);
  transpose_cast<<<dim3(H / 32, H / 32), 256, 0, stream>>>(Wq, WqTb, H, H);

  const float qk_scale = 0.08838834764831845f;  // 128^-0.5
  // W[o,h] = s * sum_d Wo[o,d] * Wq[d,h]  (A=Wo native, B=Wq^T)
  gemm_bt<1><<<(H / 128) * (H / 128), 256, 0, stream>>>(Wob, WqTb, (void*)Wb, H, H, H, qk_scale);
  // out[m,o] = sum_h X[m,h] * W[o,h]
  gemm_bt<0><<<(H / 128) * (M / 128), 256, 0, stream>>>(Xb, Wb, (void*)out, M, H, H, 1.0f);

  // kv_cache passthrough: overwrite the tail (including the Wb scratch region)
  hipMemcpyAsync(out + OUT_ELEMS, kv, (size_t)in_sizes[4] * sizeof(float),
                 hipMemcpyDeviceToDevice, stream);
}

// Round 3
// 358.246 us; speedup vs baseline: 1.3640x; 1.0606x over previous
//
#include <hip/hip_runtime.h>

// ---------------------------------------------------------------------------
// EdgeLLMAttentionTRTNative: out = X @ (s*Wo@Wq)^T + kv_cache passthrough.
// Round 3: big GEMM -> deep-pipelined 256x128 tile, BK=32, 8 waves, 4-slot
// LDS ring, counted vmcnt(8), raw s_barrier, setprio, T2 chunk-XOR swizzle
// (pre-swizzled global source + swizzled ds_read). Small GEMM keeps the m97
// structure + swizzle.
// ---------------------------------------------------------------------------

typedef __attribute__((ext_vector_type(8))) __bf16 bf16x8;
typedef __attribute__((ext_vector_type(4))) float f32x4;

__device__ __forceinline__ unsigned short f2bf(float f) {
  union { float f; unsigned u; } v; v.f = f;
  unsigned r = v.u + 0x7fffu + ((v.u >> 16) & 1u);   // round-to-nearest-even
  return (unsigned short)(r >> 16);
}

__global__ void cast_f32_to_bf16(const float4* __restrict__ in,
                                 ushort4* __restrict__ out, int n4) {
  int i = blockIdx.x * blockDim.x + threadIdx.x;
  int stride = gridDim.x * blockDim.x;
  for (; i < n4; i += stride) {
    float4 v = in[i];
    ushort4 o;
    o.x = f2bf(v.x); o.y = f2bf(v.y); o.z = f2bf(v.z); o.w = f2bf(v.w);
    out[i] = o;
  }
}

// out (C x R, bf16) = transpose of in (R x C, fp32)
__global__ void transpose_cast(const float* __restrict__ in,
                               ushort* __restrict__ out, int R, int C) {
  __shared__ float tile[32][33];
  const int tc = blockIdx.x * 32;
  const int tr = blockIdx.y * 32;
  const int lx = threadIdx.x & 31;
  const int ly = threadIdx.x >> 5;
#pragma unroll
  for (int i = 0; i < 32; i += 8)
    tile[ly + i][lx] = in[(size_t)(tr + ly + i) * C + (tc + lx)];
  __syncthreads();
#pragma unroll
  for (int i = 0; i < 32; i += 8)
    out[(size_t)(tc + ly + i) * R + (tr + lx)] = f2bf(tile[lx][ly + i]);
}

typedef const __attribute__((address_space(1))) void* gptr_t;
typedef __attribute__((address_space(3))) void* lptr_t;

__device__ __forceinline__ void gload16(const void* g, void* l) {
  __builtin_amdgcn_global_load_lds((gptr_t)g, (lptr_t)l, 16, 0, 0);
}

// raw barrier with compiler memory fences (no vmcnt(0) drain)
__device__ __forceinline__ void bar() {
  asm volatile("" ::: "memory");
  __builtin_amdgcn_s_barrier();
  asm volatile("" ::: "memory");
}

// ---------------------------------------------------------------------------
// Big GEMM: C(f32) = A(MxK) * B(NxK)^T, bf16 inputs. BM=256 BN=128 BK=32.
// 8 waves (4M x 2N), per-wave 64x64 output, acc[4][4].
// 4-slot LDS ring: slot = A(256x32 = 16KB) + B(128x32 = 8KB) = 24KB; x4 = 96KB.
// Stage tile t+3 while computing tile t; slot[(t+3)&3] freed at end of t-1.
// vmcnt(8): allow t+1(3)+t+2(3)+t+3(2 so far) outstanding -> tile t landed.
// T2 swizzle: stored 16B-chunk = logical ^ ((row>>1)&3); both sides.
// ---------------------------------------------------------------------------
__global__ __launch_bounds__(512, 2)
void gemm_big(const ushort* __restrict__ A, const ushort* __restrict__ B,
              float* __restrict__ C, int M, int N, int K) {
  __shared__ __align__(16) ushort lds[4 * 12288];   // 98304 B

  const int t    = threadIdx.x;
  const int w    = t >> 6;
  const int lane = t & 63;
  const int wr   = w >> 1;             // 0..3 (M)
  const int wc   = w & 1;              // 0..1 (N)
  const int fr   = lane & 15;
  const int g    = lane >> 4;          // kq group 0..3

  // XCD-aware bijective swizzle: nwg = 768, %8 == 0.
  const int nwg = gridDim.x;
  const int cpx = nwg >> 3;
  const int wg  = (blockIdx.x & 7) * cpx + (blockIdx.x >> 3);
  const int nbx = N >> 7;              // 24
  const int bx  = wg % nbx, by = wg / nbx;
  const int rowBase = by * 256, colBase = bx * 128;

  // Staging source (pre-swizzled global address; LDS dest stays linear).
  // Thread t stages LDS bytes [t*16, t*16+16): row = base + t>>2, stored
  // chunk = t&3, so logical chunk = (t&3) ^ ((t>>3)&3).
  const int srow = t >> 2;                              // 0..127
  const int scol = ((t & 3) ^ ((t >> 3) & 3)) << 3;     // element col
  const ushort* Ag0 = A + (size_t)(rowBase + srow) * K + scol;
  const ushort* Ag1 = A + (size_t)(rowBase + 128 + srow) * K + scol;
  const ushort* Bg  = B + (size_t)(colBase + srow) * K + scol;
  const int wbase = w << 10;           // wave-uniform LDS offset (lane*16 by HW)

  // Fragment read offsets (bytes within slot); (row>>1)&3 == (fr>>1)&3.
  const int swz  = (g ^ ((fr >> 1) & 3)) << 4;
  const int aOff = (wr * 64 + fr) * 64 + swz;           // + m*1024
  const int bOff = 16384 + (wc * 64 + fr) * 64 + swz;   // + n*1024

#define STAGE_A(kt) do { \
    char* s_ = (char*)lds + (((kt) & 3) * 24576) + wbase; \
    const int k_ = (kt) << 5; \
    gload16(Ag0 + k_, s_); \
    gload16(Ag1 + k_, s_ + 8192); \
  } while (0)
#define STAGE_B(kt) do { \
    char* s_ = (char*)lds + (((kt) & 3) * 24576) + 16384 + wbase; \
    gload16(Bg + ((kt) << 5), s_); \
  } while (0)

  f32x4 acc[4][4];
#pragma unroll
  for (int m = 0; m < 4; ++m)
#pragma unroll
    for (int n = 0; n < 4; ++n)
      acc[m][n] = f32x4{0.f, 0.f, 0.f, 0.f};

  const int nt = K >> 5;               // 96
  STAGE_A(0); STAGE_B(0);
  STAGE_A(1); STAGE_B(1);
  STAGE_A(2); STAGE_B(2);

  for (int kt = 0; kt < nt; ++kt) {
    const char* sb = (const char*)lds + (kt & 3) * 24576;
    const int pf = kt + 3;
    if (pf < nt) STAGE_A(pf);
    asm volatile("s_waitcnt vmcnt(8)" ::: "memory");
    bar();                             // tile kt visible to all waves
    // phase 1: read B frags + A frags m0,m1; MFMA m0,m1 x n0..3
    bf16x8 b0 = *(const bf16x8*)(sb + bOff);
    bf16x8 b1 = *(const bf16x8*)(sb + bOff + 1024);
    bf16x8 b2 = *(const bf16x8*)(sb + bOff + 2048);
    bf16x8 b3 = *(const bf16x8*)(sb + bOff + 3072);
    bf16x8 a0 = *(const bf16x8*)(sb + aOff);
    bf16x8 a1 = *(const bf16x8*)(sb + aOff + 1024);
    __builtin_amdgcn_s_setprio(1);
    acc[0][0] = __builtin_amdgcn_mfma_f32_16x16x32_bf16(a0, b0, acc[0][0], 0, 0, 0);
    acc[0][1] = __builtin_amdgcn_mfma_f32_16x16x32_bf16(a0, b1, acc[0][1], 0, 0, 0);
    acc[0][2] = __builtin_amdgcn_mfma_f32_16x16x32_bf16(a0, b2, acc[0][2], 0, 0, 0);
    acc[0][3] = __builtin_amdgcn_mfma_f32_16x16x32_bf16(a0, b3, acc[0][3], 0, 0, 0);
    acc[1][0] = __builtin_amdgcn_mfma_f32_16x16x32_bf16(a1, b0, acc[1][0], 0, 0, 0);
    acc[1][1] = __builtin_amdgcn_mfma_f32_16x16x32_bf16(a1, b1, acc[1][1], 0, 0, 0);
    acc[1][2] = __builtin_amdgcn_mfma_f32_16x16x32_bf16(a1, b2, acc[1][2], 0, 0, 0);
    acc[1][3] = __builtin_amdgcn_mfma_f32_16x16x32_bf16(a1, b3, acc[1][3], 0, 0, 0);
    __builtin_amdgcn_s_setprio(0);
    bar();                             // phase boundary
    // phase 2: stage B of t+3, read A frags m2,m3; MFMA m2,m3 x n0..3
    if (pf < nt) STAGE_B(pf);
    bf16x8 a2 = *(const bf16x8*)(sb + aOff + 2048);
    bf16x8 a3 = *(const bf16x8*)(sb + aOff + 3072);
    __builtin_amdgcn_s_setprio(1);
    acc[2][0] = __builtin_amdgcn_mfma_f32_16x16x32_bf16(a2, b0, acc[2][0], 0, 0, 0);
    acc[2][1] = __builtin_amdgcn_mfma_f32_16x16x32_bf16(a2, b1, acc[2][1], 0, 0, 0);
    acc[2][2] = __builtin_amdgcn_mfma_f32_16x16x32_bf16(a2, b2, acc[2][2], 0, 0, 0);
    acc[2][3] = __builtin_amdgcn_mfma_f32_16x16x32_bf16(a2, b3, acc[2][3], 0, 0, 0);
    acc[3][0] = __builtin_amdgcn_mfma_f32_16x16x32_bf16(a3, b0, acc[3][0], 0, 0, 0);
    acc[3][1] = __builtin_amdgcn_mfma_f32_16x16x32_bf16(a3, b1, acc[3][1], 0, 0, 0);
    acc[3][2] = __builtin_amdgcn_mfma_f32_16x16x32_bf16(a3, b2, acc[3][2], 0, 0, 0);
    acc[3][3] = __builtin_amdgcn_mfma_f32_16x16x32_bf16(a3, b3, acc[3][3], 0, 0, 0);
    __builtin_amdgcn_s_setprio(0);
    bar();                             // end of tile: slot[kt&3] reads done
  }
#undef STAGE_A
#undef STAGE_B

  // C/D layout: col = lane&15, row = (lane>>4)*4 + i
  const int orow = rowBase + wr * 64 + (g << 2);
  const int ocol = colBase + wc * 64 + fr;
#pragma unroll
  for (int m = 0; m < 4; ++m)
#pragma unroll
    for (int n = 0; n < 4; ++n)
#pragma unroll
      for (int i = 0; i < 4; ++i)
        C[(size_t)(orow + m * 16 + i) * N + (ocol + n * 16)] = acc[m][n][i];
}

// ---------------------------------------------------------------------------
// Small GEMM (m97 structure + T2 swizzle): C = A(MxK)*B(NxK)^T, bf16 out.
// ---------------------------------------------------------------------------
template <int OUT_BF16>
__global__ void gemm_bt(const ushort* __restrict__ A, const ushort* __restrict__ B,
                        void* __restrict__ Cv, int M, int N, int K, float scale) {
  __shared__ __align__(16) ushort As[128 * 32];
  __shared__ __align__(16) ushort Bs[128 * 32];

  const int t    = threadIdx.x;
  const int w    = t >> 6;
  const int lane = t & 63;
  const int wr   = w >> 1, wc = w & 1;
  const int fr   = lane & 15;
  const int g    = lane >> 4;

  const int nwg  = gridDim.x;
  const int cpx  = nwg >> 3;
  const int wg   = (blockIdx.x & 7) * cpx + (blockIdx.x >> 3);
  const int nbx  = N >> 7;
  const int bx   = wg % nbx;
  const int by   = wg / nbx;
  const int rowBase = by * 128;
  const int colBase = bx * 128;

  // Pre-swizzled staging source: stored chunk t&3 holds logical chunk
  // (t&3)^((t>>3)&3); rows r0 = t>>2, r1 = 64 + t>>2 (same XOR class).
  const int r0 = t >> 2;
  const int sc = ((t & 3) ^ ((t >> 3) & 3)) << 3;
  const ushort* Ag0 = A + (size_t)(rowBase + r0) * K + sc;
  const ushort* Ag1 = A + (size_t)(rowBase + 64 + r0) * K + sc;
  const ushort* Bg0 = B + (size_t)(colBase + r0) * K + sc;
  const ushort* Bg1 = B + (size_t)(colBase + 64 + r0) * K + sc;
  ushort* Al0 = &As[w * 512];
  ushort* Al1 = &As[2048 + w * 512];
  ushort* Bl0 = &Bs[w * 512];
  ushort* Bl1 = &Bs[2048 + w * 512];

  const int swz8 = (g ^ ((fr >> 1) & 3)) << 3;   // swizzled element offset

  f32x4 acc[4][4];
#pragma unroll
  for (int m = 0; m < 4; ++m)
#pragma unroll
    for (int n = 0; n < 4; ++n)
      acc[m][n] = f32x4{0.f, 0.f, 0.f, 0.f};

  for (int k0 = 0; k0 < K; k0 += 32) {
    __syncthreads();
    gload16(Ag0 + k0, Al0);
    gload16(Ag1 + k0, Al1);
    gload16(Bg0 + k0, Bl0);
    gload16(Bg1 + k0, Bl1);
    __syncthreads();

    bf16x8 a[4], b[4];
#pragma unroll
    for (int m = 0; m < 4; ++m)
      a[m] = *(const bf16x8*)&As[(wr * 64 + m * 16 + fr) * 32 + swz8];
#pragma unroll
    for (int n = 0; n < 4; ++n)
      b[n] = *(const bf16x8*)&Bs[(wc * 64 + n * 16 + fr) * 32 + swz8];

#pragma unroll
    for (int m = 0; m < 4; ++m)
#pragma unroll
      for (int n = 0; n < 4; ++n)
        acc[m][n] = __builtin_amdgcn_mfma_f32_16x16x32_bf16(a[m], b[n], acc[m][n], 0, 0, 0);
  }

  const int orow = rowBase + wr * 64 + (g << 2);
  const int ocol = colBase + wc * 64 + fr;
#pragma unroll
  for (int m = 0; m < 4; ++m)
#pragma unroll
    for (int n = 0; n < 4; ++n)
#pragma unroll
      for (int i = 0; i < 4; ++i) {
        const size_t idx = (size_t)(orow + m * 16 + i) * N + (ocol + n * 16);
        float v = acc[m][n][i] * scale;
        if (OUT_BF16) ((ushort*)Cv)[idx] = f2bf(v);
        else          ((float*)Cv)[idx]  = v;
      }
}

extern "C" void kernel_launch(void* const* d_in, const int* in_sizes, int n_in,
                              void* d_out, int out_size, void* d_ws, size_t ws_size,
                              hipStream_t stream) {
  const float* hs = (const float*)d_in[0];   // (4,2048,3072)
  const float* kv = (const float*)d_in[4];   // (4,2,8,4096,128)
  const float* Wq = (const float*)d_in[5];   // (3072,3072) (d,h)
  const float* Wo = (const float*)d_in[8];   // (3072,3072) (o,d)

  const int M = 8192, H = 3072;
  const int OUT_ELEMS = M * H;

  float* out = (float*)d_out;

  ushort* Xb   = (ushort*)d_ws;
  ushort* Wob  = Xb + (size_t)M * H;
  ushort* WqTb = Wob + (size_t)H * H;
  // Fused weight W = s*Wo@Wq (bf16) in the kv-tail of d_out; overwritten by
  // the kv_cache copy afterwards (stream-ordered).
  ushort* Wb   = (ushort*)(out + OUT_ELEMS);

  cast_f32_to_bf16<<<2048, 256, 0, stream>>>((const float4*)hs, (ushort4*)Xb, (M * H) / 4);
  cast_f32_to_bf16<<<1024, 256, 0, stream>>>((const float4*)Wo, (ushort4*)Wob, (H * H) / 4);
  transpose_cast<<<dim3(H / 32, H / 32), 256, 0, stream>>>(Wq, WqTb, H, H);

  const float qk_scale = 0.08838834764831845f;  // 128^-0.5
  // W[o,h] = s * sum_d Wo[o,d] * Wq[d,h]
  gemm_bt<1><<<(H / 128) * (H / 128), 256, 0, stream>>>(Wob, WqTb, (void*)Wb, H, H, H, qk_scale);
  // out[m,o] = sum_h X[m,h] * W[o,h]  — deep-pipelined kernel
  gemm_big<<<(M / 256) * (H / 128), 512, 0, stream>>>(Xb, Wb, out, M, H, H);

  hipMemcpyAsync(out + OUT_ELEMS, kv, (size_t)in_sizes[4] * sizeof(float),
                 hipMemcpyDeviceToDevice, stream);
}

// Round 5
// 328.414 us; speedup vs baseline: 1.4879x; 1.0908x over previous
//
#include <hip/hip_runtime.h>

// ---------------------------------------------------------------------------
// EdgeLLMAttentionTRTNative: out = X @ (s*Wo@Wq)^T + kv_cache passthrough.
// Round 5: fix round-4 race. Stage placement now respects region lifetimes:
//   B(T+2)@P3 (B freed after P1), A_LOW+A_HIGH(T+2)@P4 (A freed after P3).
//   vmcnt(3) steady (B(T+2) may stay in flight; tile T+1 landed), vmcnt(0)
//   for last two tiles. Everything else as round 4: BM=256 BN=192 BK=64,
//   8 waves (2Mx4N), 2-buffer LDS 112KB, 4 phases/tile, chunk-XOR swizzle.
// ---------------------------------------------------------------------------

typedef __attribute__((ext_vector_type(8))) __bf16 bf16x8;
typedef __attribute__((ext_vector_type(4))) float f32x4;

__device__ __forceinline__ unsigned short f2bf(float f) {
  union { float f; unsigned u; } v; v.f = f;
  unsigned r = v.u + 0x7fffu + ((v.u >> 16) & 1u);   // round-to-nearest-even
  return (unsigned short)(r >> 16);
}

__global__ void cast_f32_to_bf16(const float4* __restrict__ in,
                                 ushort4* __restrict__ out, int n4) {
  int i = blockIdx.x * blockDim.x + threadIdx.x;
  int stride = gridDim.x * blockDim.x;
  for (; i < n4; i += stride) {
    float4 v = in[i];
    ushort4 o;
    o.x = f2bf(v.x); o.y = f2bf(v.y); o.z = f2bf(v.z); o.w = f2bf(v.w);
    out[i] = o;
  }
}

// out (C x R, bf16) = transpose of in (R x C, fp32)
__global__ void transpose_cast(const float* __restrict__ in,
                               ushort* __restrict__ out, int R, int C) {
  __shared__ float tile[32][33];
  const int tc = blockIdx.x * 32;
  const int tr = blockIdx.y * 32;
  const int lx = threadIdx.x & 31;
  const int ly = threadIdx.x >> 5;
#pragma unroll
  for (int i = 0; i < 32; i += 8)
    tile[ly + i][lx] = in[(size_t)(tr + ly + i) * C + (tc + lx)];
  __syncthreads();
#pragma unroll
  for (int i = 0; i < 32; i += 8)
    out[(size_t)(tc + ly + i) * R + (tr + lx)] = f2bf(tile[lx][ly + i]);
}

typedef const __attribute__((address_space(1))) void* gptr_t;
typedef __attribute__((address_space(3))) void* lptr_t;

__device__ __forceinline__ void gload16(const void* g, void* l) {
  __builtin_amdgcn_global_load_lds((gptr_t)g, (lptr_t)l, 16, 0, 0);
}

#define BAR   do { asm volatile("" ::: "memory"); __builtin_amdgcn_s_barrier(); asm volatile("" ::: "memory"); } while (0)
#define LGKM0 asm volatile("s_waitcnt lgkmcnt(0)" ::: "memory")
#define VM(n) asm volatile("s_waitcnt vmcnt(" #n ")" ::: "memory")

// ---------------------------------------------------------------------------
// Big GEMM: C(f32) = A(MxK) * B(NxK)^T, bf16 in. BM=256 BN=192 BK=64.
// 8 waves 2Mx4N; per-wave 128x48 out -> acc[8][3].
// LDS buffer: A[256][64] (32KB) + B[192][64] (24KB); 2 buffers = 112KB.
// Swizzle: 16B chunk c of row r stored at c^(r&7) (pre-swizzled global src).
// Region lifetimes within tile T (buffer bo = T&1; T+2 also targets bo):
//   B read kh0@P4(prev), kh1@P1  -> free P2+   -> stage B(T+2)@P3
//   A_LOW  rows 0..63 read @P4(prev),P1; rows 64..127 @P2,P3 -> free P4
//   A_HIGH rows 128..191 @P4(prev),P1; rows 192..255 @P2,P3  -> free P4
//     -> stage A_LOW(T+2)+A_HIGH(T+2)@P4 (writes bo; P4 reads bon: disjoint)
// vmcnt(3) before end-P3 barrier: allow only B(T+2) in flight => tile T+1
// (7 loads, issued >= 4 phases earlier) landed before P4 read-ahead.
// Tail (T >= nt-2): B(T+2) not staged => vmcnt(0) to drain A(T+1).
// ---------------------------------------------------------------------------
__global__ __launch_bounds__(512, 2)
void gemm_big(const ushort* __restrict__ A, const ushort* __restrict__ B,
              float* __restrict__ C, int M, int N, int K) {
  __shared__ __align__(16) char smem[114688];

  const int t    = threadIdx.x;
  const int w    = t >> 6;
  const int lane = t & 63;
  const int wr   = w >> 2;             // 0..1  (M: 128 rows each)
  const int wc   = w & 3;              // 0..3  (N: 48 cols each)
  const int fr   = lane & 15;
  const int g    = lane >> 4;          // 0..3

  // XCD-aware bijective swizzle: nwg = 512, %8 == 0.
  const int nwg = gridDim.x;
  const int cpx = nwg >> 3;
  const int wg  = (blockIdx.x & 7) * cpx + (blockIdx.x >> 3);
  const int nbx = N / 192;             // 16
  const int bx  = wg % nbx, by = wg / nbx;
  const int rowBase = by * 256, colBase = bx * 192;

  // Staging: pass covers 64 rows; wave w rows [w*8, w*8+8); lane l row +l>>3,
  // stored chunk l&7 holds logical chunk (l&7)^(l>>3)  (row&7 == l>>3).
  const int sr   = lane >> 3;                       // 0..7
  const int scol = ((lane & 7) ^ sr) << 3;          // pre-swizzled source col
  const ushort* Ag = A + (size_t)(rowBase + w * 8 + sr) * K + scol;
  const ushort* Bg = B + (size_t)(colBase + w * 8 + sr) * K + scol;
  const int wofs = w * 1024;                        // wave LDS byte offset

#define STAGE_A_LOW(kt)  do { char* d_ = smem + ((kt) & 1) * 57344 + wofs;          \
    const ushort* s_ = Ag + (size_t)(kt) * 64;                                      \
    gload16(s_, d_); gload16(s_ + (size_t)64 * K, d_ + 8192); } while (0)
#define STAGE_A_HIGH(kt) do { char* d_ = smem + ((kt) & 1) * 57344 + 16384 + wofs;  \
    const ushort* s_ = Ag + (size_t)128 * K + (size_t)(kt) * 64;                    \
    gload16(s_, d_); gload16(s_ + (size_t)64 * K, d_ + 8192); } while (0)
#define STAGE_B(kt)      do { char* d_ = smem + ((kt) & 1) * 57344 + 32768 + wofs;  \
    const ushort* s_ = Bg + (size_t)(kt) * 64;                                      \
    gload16(s_, d_); gload16(s_ + (size_t)64 * K, d_ + 8192);                       \
    gload16(s_ + (size_t)128 * K, d_ + 16384); } while (0)

  // Fragment read geometry (byte offsets). Row stride 128B; logical chunk
  // kh*4+g stored at (kh*4+g)^(fr&7) since row&7 == fr&7 for all frag rows.
  const int aBase = (wr * 128 + fr) * 128;
  const int bBase = 32768 + (wc * 48 + fr) * 128;
  const int cs0   = (g ^ (fr & 7)) << 4;            // kh=0
  const int cs1   = ((4 | g) ^ (fr & 7)) << 4;      // kh=1

#define READ_A(dst, bo, MH, CS) do {                                  \
    const char* p_ = smem + (bo) + aBase + (MH) * 8192 + (CS);        \
    dst[0] = *(const bf16x8*)(p_);                                    \
    dst[1] = *(const bf16x8*)(p_ + 2048);                             \
    dst[2] = *(const bf16x8*)(p_ + 4096);                             \
    dst[3] = *(const bf16x8*)(p_ + 6144); } while (0)
#define READ_B(dst, bo, CS) do {                                      \
    const char* p_ = smem + (bo) + bBase + (CS);                      \
    dst[0] = *(const bf16x8*)(p_);                                    \
    dst[1] = *(const bf16x8*)(p_ + 2048);                             \
    dst[2] = *(const bf16x8*)(p_ + 4096); } while (0)
#define MFMA_Q(MH, aset, bset) do {                                   \
    _Pragma("unroll") for (int mi_ = 0; mi_ < 4; ++mi_)               \
    _Pragma("unroll") for (int ni_ = 0; ni_ < 3; ++ni_)               \
      acc[(MH) * 4 + mi_][ni_] = __builtin_amdgcn_mfma_f32_16x16x32_bf16( \
          aset[mi_], bset[ni_], acc[(MH) * 4 + mi_][ni_], 0, 0, 0); } while (0)

  f32x4 acc[8][3];
#pragma unroll
  for (int m = 0; m < 8; ++m)
#pragma unroll
    for (int n = 0; n < 3; ++n)
      acc[m][n] = f32x4{0.f, 0.f, 0.f, 0.f};

  bf16x8 aA[4], aB[4], Bk0[3], Bk1[3];

  const int nt = K >> 6;               // 48

  // Prologue: stage tiles 0,1 fully; wait tile 0; pre-read q(0,0) regs.
  STAGE_A_LOW(0); STAGE_B(0); STAGE_A_HIGH(0);
  STAGE_A_LOW(1); STAGE_B(1); STAGE_A_HIGH(1);
  VM(7);
  BAR;
  READ_A(aA, 0, 0, cs0);
  READ_B(Bk0, 0, cs0);

  for (int T = 0; T < nt; ++T) {
    const int bo  = (T & 1) * 57344;
    const int bon = 57344 - bo;
    const bool stg = (T + 2) < nt;
    // ---- P1: compute q(mh0,kh0); read-ahead A(mh0,kh1), B(kh1)
    READ_A(aB, bo, 0, cs1);
    READ_B(Bk1, bo, cs1);
    BAR; LGKM0;
    __builtin_amdgcn_s_setprio(1); MFMA_Q(0, aA, Bk0); __builtin_amdgcn_s_setprio(0);
    BAR;
    // ---- P2: compute q(mh0,kh1); read-ahead A(mh1,kh0)
    READ_A(aA, bo, 1, cs0);
    BAR; LGKM0;
    __builtin_amdgcn_s_setprio(1); MFMA_Q(0, aB, Bk1); __builtin_amdgcn_s_setprio(0);
    BAR;
    // ---- P3: stage B(T+2) (B region freed after P1); compute q(mh1,kh0);
    //          read-ahead A(mh1,kh1); then tile-boundary vmcnt.
    if (stg) STAGE_B(T + 2);
    READ_A(aB, bo, 1, cs1);
    BAR; LGKM0;
    __builtin_amdgcn_s_setprio(1); MFMA_Q(1, aA, Bk0); __builtin_amdgcn_s_setprio(0);
    if (T < nt - 2) { VM(3); } else { VM(0); }   // tile T+1 fully landed
    BAR;
    // ---- P4: stage A_LOW+A_HIGH(T+2) (A regions freed after P3; writes bo,
    //          reads below touch bon only); compute q(mh1,kh1); read next tile.
    if (stg) { STAGE_A_LOW(T + 2); STAGE_A_HIGH(T + 2); }
    if (T + 1 < nt) { READ_A(aA, bon, 0, cs0); READ_B(Bk0, bon, cs0); }
    BAR; LGKM0;
    __builtin_amdgcn_s_setprio(1); MFMA_Q(1, aB, Bk1); __builtin_amdgcn_s_setprio(0);
    BAR;
  }

#undef STAGE_A_LOW
#undef STAGE_A_HIGH
#undef STAGE_B
#undef READ_A
#undef READ_B
#undef MFMA_Q

  // C/D layout: col = lane&15, row = (lane>>4)*4 + i
  const int orow = rowBase + wr * 128 + (g << 2);
  const int ocol = colBase + wc * 48 + fr;
#pragma unroll
  for (int mi = 0; mi < 8; ++mi)
#pragma unroll
    for (int ni = 0; ni < 3; ++ni)
#pragma unroll
      for (int i = 0; i < 4; ++i)
        C[(size_t)(orow + mi * 16 + i) * N + (ocol + ni * 16)] = acc[mi][ni][i];
}

// ---------------------------------------------------------------------------
// Small GEMM (m97 structure + T2 swizzle): C = A(MxK)*B(NxK)^T, bf16 out.
// ---------------------------------------------------------------------------
template <int OUT_BF16>
__global__ void gemm_bt(const ushort* __restrict__ A, const ushort* __restrict__ B,
                        void* __restrict__ Cv, int M, int N, int K, float scale) {
  __shared__ __align__(16) ushort As[128 * 32];
  __shared__ __align__(16) ushort Bs[128 * 32];

  const int t    = threadIdx.x;
  const int w    = t >> 6;
  const int lane = t & 63;
  const int wr   = w >> 1, wc = w & 1;
  const int fr   = lane & 15;
  const int g    = lane >> 4;

  const int nwg  = gridDim.x;
  const int cpx  = nwg >> 3;
  const int wg   = (blockIdx.x & 7) * cpx + (blockIdx.x >> 3);
  const int nbx  = N >> 7;
  const int bx   = wg % nbx;
  const int by   = wg / nbx;
  const int rowBase = by * 128;
  const int colBase = bx * 128;

  const int r0 = t >> 2;
  const int sc = ((t & 3) ^ ((t >> 3) & 3)) << 3;
  const ushort* Ag0 = A + (size_t)(rowBase + r0) * K + sc;
  const ushort* Ag1 = A + (size_t)(rowBase + 64 + r0) * K + sc;
  const ushort* Bg0 = B + (size_t)(colBase + r0) * K + sc;
  const ushort* Bg1 = B + (size_t)(colBase + 64 + r0) * K + sc;
  ushort* Al0 = &As[w * 512];
  ushort* Al1 = &As[2048 + w * 512];
  ushort* Bl0 = &Bs[w * 512];
  ushort* Bl1 = &Bs[2048 + w * 512];

  const int swz8 = (g ^ ((fr >> 1) & 3)) << 3;

  f32x4 acc[4][4];
#pragma unroll
  for (int m = 0; m < 4; ++m)
#pragma unroll
    for (int n = 0; n < 4; ++n)
      acc[m][n] = f32x4{0.f, 0.f, 0.f, 0.f};

  for (int k0 = 0; k0 < K; k0 += 32) {
    __syncthreads();
    gload16(Ag0 + k0, Al0);
    gload16(Ag1 + k0, Al1);
    gload16(Bg0 + k0, Bl0);
    gload16(Bg1 + k0, Bl1);
    __syncthreads();

    bf16x8 a[4], b[4];
#pragma unroll
    for (int m = 0; m < 4; ++m)
      a[m] = *(const bf16x8*)&As[(wr * 64 + m * 16 + fr) * 32 + swz8];
#pragma unroll
    for (int n = 0; n < 4; ++n)
      b[n] = *(const bf16x8*)&Bs[(wc * 64 + n * 16 + fr) * 32 + swz8];

#pragma unroll
    for (int m = 0; m < 4; ++m)
#pragma unroll
      for (int n = 0; n < 4; ++n)
        acc[m][n] = __builtin_amdgcn_mfma_f32_16x16x32_bf16(a[m], b[n], acc[m][n], 0, 0, 0);
  }

  const int orow = rowBase + wr * 64 + (g << 2);
  const int ocol = colBase + wc * 64 + fr;
#pragma unroll
  for (int m = 0; m < 4; ++m)
#pragma unroll
    for (int n = 0; n < 4; ++n)
#pragma unroll
      for (int i = 0; i < 4; ++i) {
        const size_t idx = (size_t)(orow + m * 16 + i) * N + (ocol + n * 16);
        float v = acc[m][n][i] * scale;
        if (OUT_BF16) ((ushort*)Cv)[idx] = f2bf(v);
        else          ((float*)Cv)[idx]  = v;
      }
}

extern "C" void kernel_launch(void* const* d_in, const int* in_sizes, int n_in,
                              void* d_out, int out_size, void* d_ws, size_t ws_size,
                              hipStream_t stream) {
  const float* hs = (const float*)d_in[0];   // (4,2048,3072)
  const float* kv = (const float*)d_in[4];   // (4,2,8,4096,128)
  const float* Wq = (const float*)d_in[5];   // (3072,3072) (d,h)
  const float* Wo = (const float*)d_in[8];   // (3072,3072) (o,d)

  const int M = 8192, H = 3072;
  const int OUT_ELEMS = M * H;

  float* out = (float*)d_out;

  ushort* Xb   = (ushort*)d_ws;
  ushort* Wob  = Xb + (size_t)M * H;
  ushort* WqTb = Wob + (size_t)H * H;
  // Fused weight W = s*Wo@Wq (bf16) in the kv-tail of d_out; overwritten by
  // the kv_cache copy afterwards (stream-ordered).
  ushort* Wb   = (ushort*)(out + OUT_ELEMS);

  cast_f32_to_bf16<<<2048, 256, 0, stream>>>((const float4*)hs, (ushort4*)Xb, (M * H) / 4);
  cast_f32_to_bf16<<<1024, 256, 0, stream>>>((const float4*)Wo, (ushort4*)Wob, (H * H) / 4);
  transpose_cast<<<dim3(H / 32, H / 32), 256, 0, stream>>>(Wq, WqTb, H, H);

  const float qk_scale = 0.08838834764831845f;  // 128^-0.5
  // W[o,h] = s * sum_d Wo[o,d] * Wq[d,h]
  gemm_bt<1><<<(H / 128) * (H / 128), 256, 0, stream>>>(Wob, WqTb, (void*)Wb, H, H, H, qk_scale);
  // out[m,o] = sum_h X[m,h] * W[o,h]  — 4-phase pipelined kernel
  gemm_big<<<(M / 256) * (H / 192), 512, 0, stream>>>(Xb, Wb, out, M, H, H);

  hipMemcpyAsync(out + OUT_ELEMS, kv, (size_t)in_sizes[4] * sizeof(float),
                 hipMemcpyDeviceToDevice, stream);
}